// Round 16
// baseline (99.105 us; speedup 1.0000x reference)
//
#include <hip/hip_runtime.h>
#include <cmath>
#include <cstdint>

typedef __attribute__((ext_vector_type(8))) short short8;
typedef __attribute__((ext_vector_type(4))) float f32x4;
typedef __attribute__((ext_vector_type(2))) unsigned int u32x2;
typedef __attribute__((ext_vector_type(4))) unsigned int u32x4;

struct Lams { float v[8]; };

#define NC 8
#define NB 4
#define NT 8192
#define ND 64
#define CL 256               // chunk length (rows per pass)
#define NCHUNK 32            // chunks per sequence
#define NKK 16               // chunk-pairs per sequence (blocks per seq)
#define NBLK (2 * NC * NB * NKK)     // 1024 blocks (= resident capacity)
#define NSLOT (2 * NC * NB * NCHUNK) // 2048 chunk slots
#define NWAVE 8              // waves per block
#define TR32 132             // u32 words per column (264 bf16 rows), 528 B

// packed f32x2 -> bf16x2 (RNE), gfx950 v_cvt_pk_bf16_f32
__device__ __forceinline__ uint32_t pk2(float lo, float hi) {
    uint32_t r;
    asm("v_cvt_pk_bf16_f32 %0, %1, %2" : "=v"(r) : "v"(lo), "v"(hi));
    return r;
}

__device__ __forceinline__ float bf2f(unsigned short s) {
    return __builtin_bit_cast(float, (uint32_t)s << 16);
}
__device__ __forceinline__ float bflo(uint32_t u) { return bf2f((unsigned short)(u & 0xFFFFu)); }
__device__ __forceinline__ float bfhi(uint32_t u) { return bf2f((unsigned short)(u >> 16)); }

__device__ __forceinline__ short8 cvt8(f32x4 a, f32x4 b) {
    union { short8 s8; uint32_t u[4]; } t;
    t.u[0] = pk2(a[0], a[1]); t.u[1] = pk2(a[2], a[3]);
    t.u[2] = pk2(b[0], b[1]); t.u[3] = pk2(b[2], b[3]);
    return t.s8;
}

// Round-14 persistent schedule (1024 blocks, passes kk & kk+16, fence-free
// decoupled lookback) + column-major LDS transpose, re-landed safely after
// the r15 NaN: (a) tbuf is uint32_t with ONLY u32-family accesses (no
// short/uint cross-type punning), (b) explicit barriers after staging and
// after the gate phase (no reliance on wave-local LDS ordering). One u32 =
// 2 consecutive bf16 rows of one column; column stride 132 u32 = 528 B.
// A-fragments read direct from global (round-1 proven path, L2-hot).
// ws layout: int flags[NSLOT] @0 (8 KiB); float E[NSLOT][ND] @16KiB.
__global__ __launch_bounds__(512, 4) void k1_fused(
    const float* __restrict__ x, const float* __restrict__ Wf,
    const float* __restrict__ bf, const float* __restrict__ Wb,
    const float* __restrict__ bb, float* __restrict__ out,
    int* __restrict__ flags, float* __restrict__ evals, Lams lams)
{
    __shared__ uint32_t tbuf[ND * TR32];        // col-major, 2 rows per u32
    __shared__ float ends_lds[NWAVE][ND];       // per-wave sub-chunk ends (f32)
    __shared__ float hprev_lds[ND];             // resolved cross-chunk carry

    const int tid  = threadIdx.x;
    const int lane = tid & 63;
    const int w    = tid >> 6;          // wave 0..7

    int idx = blockIdx.x;
    const int kk  = idx & (NKK - 1); idx >>= 4;
    const int b   = idx & (NB - 1);  idx >>= 2;
    const int c   = idx & (NC - 1);  idx >>= 3;
    const int dir = idx;                // 0 fwd, 1 bwd

    const float lam = lams.v[c];
    const float* W    = (dir ? Wb : Wf) + c * ND * ND;
    const float* bias = (dir ? bb : bf) + c * ND;
    const float* xb   = x + (size_t)(c * NB + b) * NT * ND;
    float* ob = out + (size_t)dir * (size_t)(NC*NB*NT*ND)
                    + (size_t)(c * NB + b) * NT * ND;
    const int seqbase = (int)(blockIdx.x >> 4) * NCHUNK;  // slot base of seq

    const int er = lane & 15;   // row/col within 16-tile
    const int ks = lane >> 4;   // k-segment 0..3
    const int r0 = w * 32;      // this wave's rows [r0, r0+32) within tile

    // ---- B fragments from W (L2-hot) + bias: once per block ----
    short8 bfrag[4][2];
    #pragma unroll
    for (int et = 0; et < 4; ++et) {
        const float* wr = W + (et*16 + er) * ND + ks * 8;
        #pragma unroll
        for (int kq = 0; kq < 2; ++kq) {
            f32x4 lo = *reinterpret_cast<const f32x4*>(wr + kq*32);
            f32x4 hi = *reinterpret_cast<const f32x4*>(wr + kq*32 + 4);
            bfrag[et][kq] = cvt8(lo, hi);
        }
    }
    float bias_r[4];
    #pragma unroll
    for (int et = 0; et < 4; ++et) bias_r[et] = bias[et*16 + er];

    float lam32 = lam*lam; lam32*=lam32; lam32*=lam32; lam32*=lam32; lam32*=lam32;

    #pragma unroll 1
    for (int pass = 0; pass < 2; ++pass) {
        const int g   = kk + NKK * pass;   // global chunk index 0..31
        const int tr0 = g * CL;

        // ---- stage: lane=col, this wave's 32 rows -> tbuf (b128) ----
        {
            const float* sp = dir
                ? xb + (size_t)(NT-1 - (tr0 + r0)) * ND + lane
                : xb + (size_t)(tr0 + r0) * ND + lane;
            const ptrdiff_t step = dir ? -(ptrdiff_t)ND : (ptrdiff_t)ND;
            #pragma unroll
            for (int q = 0; q < 4; ++q) {
                float v[8];
                #pragma unroll
                for (int i = 0; i < 8; ++i)
                    v[i] = sp[(ptrdiff_t)(q*8 + i) * step];
                u32x4 pk = { pk2(v[0], v[1]), pk2(v[2], v[3]),
                             pk2(v[4], v[5]), pk2(v[6], v[7]) };
                *reinterpret_cast<u32x4*>(&tbuf[lane * TR32 + 16*w + 4*q]) = pk;
            }
        }
        __syncthreads();   // staged tile visible to all

        // ---- MFMA logits (A-frags direct from global) + gate in tbuf ----
        #pragma unroll
        for (int u = 0; u < 2; ++u) {
            const int trow = tr0 + r0 + u*16;
            short8 afrag[2];
            {
                const int tg = dir ? (NT-1 - (trow + er)) : (trow + er);
                const float* xr = xb + (size_t)tg * ND + ks * 8;
                #pragma unroll
                for (int kq = 0; kq < 2; ++kq) {
                    f32x4 lo = *reinterpret_cast<const f32x4*>(xr + kq*32);
                    f32x4 hi = *reinterpret_cast<const f32x4*>(xr + kq*32 + 4);
                    afrag[kq] = cvt8(lo, hi);
                }
            }
            #pragma unroll
            for (int et = 0; et < 4; ++et) {
                f32x4 acc = {0.f, 0.f, 0.f, 0.f};
                acc = __builtin_amdgcn_mfma_f32_16x16x32_bf16(afrag[0], bfrag[et][0], acc, 0,0,0);
                acc = __builtin_amdgcn_mfma_f32_16x16x32_bf16(afrag[1], bfrag[et][1], acc, 0,0,0);
                const int col = et*16 + er;
                // C/D: col = lane&15 (=er), row = ks*4 + r; rows are packed
                // 2-per-u32 -> u32 index = 16w + 8u + 2ks (+ j), j=r/2
                uint32_t* tb = &tbuf[col * TR32 + 16*w + 8*u + 2*ks];
                u32x2 xv2 = *reinterpret_cast<const u32x2*>(tb);
                float xv[4] = { bflo(xv2[0]), bfhi(xv2[0]),
                                bflo(xv2[1]), bfhi(xv2[1]) };
                float gated[4];
                #pragma unroll
                for (int r = 0; r < 4; ++r) {
                    float z  = acc[r] + bias_r[et];
                    float gg = __builtin_amdgcn_rcpf(1.0f + __expf(-z));
                    gated[r] = gg * xv[r];
                }
                u32x2 gp = { pk2(gated[0], gated[1]), pk2(gated[2], gated[3]) };
                *reinterpret_cast<u32x2*>(tb) = gp;
            }
        }
        __syncthreads();   // gated tile visible to all

        // ---- scan: lane=col, b128 read/modify/write of own rows ----
        {
            float h = 0.f;
            uint32_t* tc = &tbuf[lane * TR32 + 16*w];
            #pragma unroll
            for (int q = 0; q < 4; ++q) {
                u32x4 vv = *reinterpret_cast<const u32x4*>(&tc[4*q]);
                u32x4 hh;
                #pragma unroll
                for (int j = 0; j < 4; ++j) {
                    float h0 = fmaf(h, lam, bflo(vv[j]));
                    float h1 = fmaf(h0, lam, bfhi(vv[j]));
                    hh[j] = pk2(h0, h1);
                    h = h1;
                }
                *reinterpret_cast<u32x4*>(&tc[4*q]) = hh;
            }
            ends_lds[w][lane] = h;   // f32 chain for E/carry precision
        }
        __syncthreads();

        // ---- wave 7: publish chunk end, decoupled lookback (r14 form) ----
        if (w == NWAVE - 1) {
            float carryW = 0.f;
            #pragma unroll
            for (int j = 0; j < NWAVE - 1; ++j)
                carryW = fmaf(carryW, lam32, ends_lds[j][lane]);
            float E = fmaf(carryW, lam32, ends_lds[NWAVE-1][lane]);  // local end

            float Hprev = 0.f;
            if (c != 0) {
                const int slot = seqbase + g;
                // publish E via relaxed agent atomics (no fence: r5 lesson)
                __hip_atomic_store(&evals[(size_t)slot * ND + lane], E,
                                   __ATOMIC_RELAXED, __HIP_MEMORY_SCOPE_AGENT);
                asm volatile("s_waitcnt vmcnt(0)" ::: "memory");
                if (lane == 0)
                    __hip_atomic_store(&flags[slot], 1, __ATOMIC_RELAXED,
                                       __HIP_MEMORY_SCOPE_AGENT);
                if (g != 0) {
                    // parallel spin: one predecessor flag per lane (distinct
                    // addresses; r8 lesson: never same-address multi-lane)
                    if (lane < g) {
                        while (__hip_atomic_load(&flags[seqbase + lane], __ATOMIC_RELAXED,
                                                 __HIP_MEMORY_SCOPE_AGENT) == 0)
                            __builtin_amdgcn_s_sleep(8);
                    }
                    asm volatile("" ::: "memory");
                    // quad-grouped Horner, plain cached loads (write-once data)
                    const float* eb = evals + (size_t)seqbase * ND;
                    float l1 = lam32*lam32; l1 *= l1; l1 *= l1;   // lam^256
                    float l4 = l1 * l1; l4 *= l4;                 // lam^1024
                    float P = 0.f;
                    int j = 0;
                    const int rem = g & 3;
                    for (; j < rem; ++j)
                        P = fmaf(P, l1, eb[(size_t)j * ND + lane]);
                    for (; j < g; j += 4) {
                        float e0 = eb[(size_t)(j+0) * ND + lane];
                        float e1 = eb[(size_t)(j+1) * ND + lane];
                        float e2 = eb[(size_t)(j+2) * ND + lane];
                        float e3 = eb[(size_t)(j+3) * ND + lane];
                        float t = fmaf(fmaf(fmaf(e0, l1, e1), l1, e2), l1, e3);
                        P = fmaf(P, l4, t);
                    }
                    Hprev = P;
                }
            }
            hprev_lds[lane] = Hprev;
        }
        __syncthreads();

        // ---- epilogue: lane=col, b128 reads, coalesced dword stores ----
        {
            float cy = 0.f, pw = 1.f;
            for (int j = 0; j < w; ++j) {
                cy = fmaf(cy, lam32, ends_lds[j][lane]);
                pw *= lam32;
            }
            const float carry = fmaf(pw, hprev_lds[lane], cy);

            float* p = dir
                ? ob + (size_t)(NT-1 - (tr0 + r0)) * ND + lane
                : ob + (size_t)(tr0 + r0) * ND + lane;
            const ptrdiff_t step = dir ? -(ptrdiff_t)ND : (ptrdiff_t)ND;
            const uint32_t* tc = &tbuf[lane * TR32 + 16*w];
            float f = lam;
            #pragma unroll
            for (int q = 0; q < 4; ++q) {
                u32x4 vv = *reinterpret_cast<const u32x4*>(&tc[4*q]);
                #pragma unroll
                for (int j = 0; j < 4; ++j) {
                    p[(ptrdiff_t)(q*8 + 2*j) * step]     = fmaf(f, carry, bflo(vv[j]));
                    f *= lam;
                    p[(ptrdiff_t)(q*8 + 2*j + 1) * step] = fmaf(f, carry, bfhi(vv[j]));
                    f *= lam;
                }
            }
        }
        __syncthreads();   // tbuf/ends_lds/hprev_lds reuse safety
    }
}

extern "C" void kernel_launch(void* const* d_in, const int* in_sizes, int n_in,
                              void* d_out, int out_size, void* d_ws, size_t ws_size,
                              hipStream_t stream)
{
    const float* x  = (const float*)d_in[0];
    const float* Wf = (const float*)d_in[1];
    const float* bf = (const float*)d_in[2];
    const float* Wb = (const float*)d_in[3];
    const float* bb = (const float*)d_in[4];
    float* out = (float*)d_out;

    int*   flags = (int*)d_ws;                         // NSLOT ints (8 KiB)
    float* evals = (float*)((char*)d_ws + 16384);      // NSLOT*ND floats (512 KiB)

    Lams lams;
    const double delta = 13.0 / 7.0;   // log2(8192)/(C-1)
    for (int c = 0; c < 8; ++c)
        lams.v[c] = (float)(1.0 - pow(2.0, -(double)c * delta));

    // reset flags every launch (graph-replay safe, on-stream)
    hipMemsetAsync(flags, 0, NSLOT * 4, stream);

    dim3 grid(NBLK);   // 1024 blocks: (dir,c,b,kk), kk fastest — all resident
    k1_fused<<<grid, 512, 0, stream>>>(x, Wf, bf, Wb, bb, out, flags, evals, lams);
}

// Round 17
// 70.325 us; speedup vs baseline: 1.4092x; 1.4092x over previous
//
#include <hip/hip_runtime.h>
#include <cmath>
#include <cstdint>

typedef __attribute__((ext_vector_type(8))) short short8;
typedef __attribute__((ext_vector_type(4))) float f32x4;
typedef __attribute__((ext_vector_type(2))) unsigned int u32x2;

struct Lams { float v[8]; };

#define NC 8
#define NB 4
#define NT 8192
#define ND 64
#define CL 256               // chunk length (rows per pass)
#define NCHUNK 32            // chunks per sequence
#define NKK 16               // chunk-pairs per sequence (blocks per seq)
#define NBLK (2 * NC * NB * NKK)     // 1024 blocks (= resident capacity)
#define NSLOT (2 * NC * NB * NCHUNK) // 2048 chunk slots
#define NWAVE 8              // waves per block
#define LDH 72               // padded LDS row stride in bf16 halves (144 B)

// packed f32x2 -> bf16x2 (RNE), gfx950 v_cvt_pk_bf16_f32
__device__ __forceinline__ uint32_t pk2(float lo, float hi) {
    uint32_t r;
    asm("v_cvt_pk_bf16_f32 %0, %1, %2" : "=v"(r) : "v"(lo), "v"(hi));
    return r;
}

__device__ __forceinline__ float bf2f(unsigned short s) {
    return __builtin_bit_cast(float, (uint32_t)s << 16);
}
__device__ __forceinline__ float bflo(uint32_t u) { return bf2f((unsigned short)(u & 0xFFFFu)); }
__device__ __forceinline__ float bfhi(uint32_t u) { return bf2f((unsigned short)(u >> 16)); }

// Round-14 base (proven best: 70.8us — persistent 1024-block schedule,
// passes kk & kk+16, fence-free decoupled lookback, row-major bf16 xbuf)
// with two r13-proven vectorizations grafted back in:
//  - staging: 8x f32x4 global loads + 8x b64 LDS writes per thread
//  - epilogue: 8x u32x2 LDS reads + 8x f32x4 global stores per thread
// and spin backoff s_sleep(2) (flag latency is on the critical path).
// r16 lesson: col-major LDS transpose = 8-way bank conflicts + extra
// barriers + extra global traffic — reverted.
// ws layout: int flags[NSLOT] @0 (8 KiB); float E[NSLOT][ND] @16KiB.
__global__ __launch_bounds__(512, 4) void k1_fused(
    const float* __restrict__ x, const float* __restrict__ Wf,
    const float* __restrict__ bf, const float* __restrict__ Wb,
    const float* __restrict__ bb, float* __restrict__ out,
    int* __restrict__ flags, float* __restrict__ evals, Lams lams)
{
    __shared__ unsigned short xbuf[CL * LDH];   // x -> gated -> h (bf16)
    __shared__ float ends_lds[NWAVE][ND];       // per-wave sub-chunk ends (f32)
    __shared__ float hprev_lds[ND];             // resolved cross-chunk carry

    const int tid  = threadIdx.x;
    const int lane = tid & 63;
    const int w    = tid >> 6;          // wave 0..7

    int idx = blockIdx.x;
    const int kk  = idx & (NKK - 1); idx >>= 4;
    const int b   = idx & (NB - 1);  idx >>= 2;
    const int c   = idx & (NC - 1);  idx >>= 3;
    const int dir = idx;                // 0 fwd, 1 bwd

    const float lam = lams.v[c];
    const float* W    = (dir ? Wb : Wf) + c * ND * ND;
    const float* bias = (dir ? bb : bf) + c * ND;
    const float* xb   = x + (size_t)(c * NB + b) * NT * ND;
    float* ob = out + (size_t)dir * (size_t)(NC*NB*NT*ND)
                    + (size_t)(c * NB + b) * NT * ND;
    const int seqbase = (int)(blockIdx.x >> 4) * NCHUNK;  // slot base of seq

    const int er = lane & 15;   // row/col within 16-tile
    const int ks = lane >> 4;   // k-segment 0..3
    const int r0 = w * 32;      // this wave's rows [r0, r0+32) within tile

    // ---- B fragments from W (L2-hot) + bias: once per block ----
    short8 bfrag[4][2];
    #pragma unroll
    for (int et = 0; et < 4; ++et) {
        const float* wr = W + (et*16 + er) * ND + ks * 8;
        #pragma unroll
        for (int kq = 0; kq < 2; ++kq) {
            f32x4 lo = *reinterpret_cast<const f32x4*>(wr + kq*32);
            f32x4 hi = *reinterpret_cast<const f32x4*>(wr + kq*32 + 4);
            union { short8 s8; uint32_t u[4]; } t;
            t.u[0] = pk2(lo[0], lo[1]); t.u[1] = pk2(lo[2], lo[3]);
            t.u[2] = pk2(hi[0], hi[1]); t.u[3] = pk2(hi[2], hi[3]);
            bfrag[et][kq] = t.s8;
        }
    }
    float bias_r[4];
    #pragma unroll
    for (int et = 0; et < 4; ++et) bias_r[et] = bias[et*16 + er];

    float lam32 = lam*lam; lam32*=lam32; lam32*=lam32; lam32*=lam32; lam32*=lam32;

    #pragma unroll 1
    for (int pass = 0; pass < 2; ++pass) {
        const int g   = kk + NKK * pass;   // global chunk index 0..31
        const int tr0 = g * CL;

        // ---- stage x rows [r0,r0+32) -> xbuf, f32x4 loads (r13 form) ----
        {
            const int sr = lane >> 4;          // row within group of 4
            const int sc = (lane & 15) * 4;    // bf16 column
            if (dir == 0) {
                const float* p = xb + (size_t)(tr0 + r0 + sr) * ND + sc;
                #pragma unroll
                for (int q = 0; q < 8; ++q) {
                    f32x4 v = *reinterpret_cast<const f32x4*>(p + (size_t)q * 4 * ND);
                    u32x2 u = { pk2(v[0], v[1]), pk2(v[2], v[3]) };
                    *reinterpret_cast<u32x2*>(&xbuf[(r0 + q*4 + sr) * LDH + sc]) = u;
                }
            } else {
                const float* p = xb + (size_t)(NT-1 - (tr0 + r0 + sr)) * ND + sc;
                #pragma unroll
                for (int q = 0; q < 8; ++q) {
                    f32x4 v = *reinterpret_cast<const f32x4*>(p - (size_t)q * 4 * ND);
                    u32x2 u = { pk2(v[0], v[1]), pk2(v[2], v[3]) };
                    *reinterpret_cast<u32x2*>(&xbuf[(r0 + q*4 + sr) * LDH + sc]) = u;
                }
            }
        }
        // no barrier: wave w staged exactly the rows it gates/scans next

        // ---- MFMA logits + sigmoid epilogue; gate xbuf in place ----
        #pragma unroll
        for (int u = 0; u < 2; ++u) {
            const int rl0 = r0 + u*16;
            short8 afrag[2];
            afrag[0] = *reinterpret_cast<const short8*>(&xbuf[(rl0 + er) * LDH + ks * 8]);
            afrag[1] = *reinterpret_cast<const short8*>(&xbuf[(rl0 + er) * LDH + 32 + ks * 8]);
            #pragma unroll
            for (int et = 0; et < 4; ++et) {
                f32x4 acc = {0.f, 0.f, 0.f, 0.f};
                acc = __builtin_amdgcn_mfma_f32_16x16x32_bf16(afrag[0], bfrag[et][0], acc, 0,0,0);
                acc = __builtin_amdgcn_mfma_f32_16x16x32_bf16(afrag[1], bfrag[et][1], acc, 0,0,0);
                const int col = et*16 + er;
                float gated[4];
                #pragma unroll
                for (int r = 0; r < 4; ++r) {
                    const int rl = rl0 + ks*4 + r;   // C/D: col=lane&15, row=(lane>>4)*4+r
                    float z  = acc[r] + bias_r[et];
                    float gg = __builtin_amdgcn_rcpf(1.0f + __expf(-z));
                    float xv = bf2f(xbuf[rl * LDH + col]);
                    gated[r] = gg * xv;
                }
                uint32_t p01 = pk2(gated[0], gated[1]);
                uint32_t p23 = pk2(gated[2], gated[3]);
                xbuf[(rl0 + ks*4 + 0) * LDH + col] = (unsigned short)(p01 & 0xFFFF);
                xbuf[(rl0 + ks*4 + 1) * LDH + col] = (unsigned short)(p01 >> 16);
                xbuf[(rl0 + ks*4 + 2) * LDH + col] = (unsigned short)(p23 & 0xFFFF);
                xbuf[(rl0 + ks*4 + 3) * LDH + col] = (unsigned short)(p23 >> 16);
            }
        }
        // no barrier: wave w only ever touched its own rows [r0, r0+32)

        // ---- wave-local scan: h in f32 reg; stored back as bf16 ----
        {
            float h = 0.f;
            #pragma unroll
            for (int i = 0; i < 32; ++i) {
                const int a = (r0 + i) * LDH + lane;
                float v = bf2f(xbuf[a]);
                h = fmaf(h, lam, v);
                xbuf[a] = (unsigned short)(pk2(h, h) & 0xFFFF);
            }
            ends_lds[w][lane] = h;   // f32 chain for E/carry precision
        }
        __syncthreads();

        // ---- wave 7: publish chunk end, decoupled lookback ----
        if (w == NWAVE - 1) {
            float carryW = 0.f;
            #pragma unroll
            for (int j = 0; j < NWAVE - 1; ++j)
                carryW = fmaf(carryW, lam32, ends_lds[j][lane]);
            float E = fmaf(carryW, lam32, ends_lds[NWAVE-1][lane]);  // local end

            float Hprev = 0.f;
            if (c != 0) {
                const int slot = seqbase + g;
                // publish E via relaxed agent atomics (no fence: r5 lesson)
                __hip_atomic_store(&evals[(size_t)slot * ND + lane], E,
                                   __ATOMIC_RELAXED, __HIP_MEMORY_SCOPE_AGENT);
                asm volatile("s_waitcnt vmcnt(0)" ::: "memory");
                if (lane == 0)
                    __hip_atomic_store(&flags[slot], 1, __ATOMIC_RELAXED,
                                       __HIP_MEMORY_SCOPE_AGENT);
                if (g != 0) {
                    // parallel spin: one predecessor flag per lane (distinct
                    // addresses; r8 lesson: never same-address multi-lane)
                    if (lane < g) {
                        while (__hip_atomic_load(&flags[seqbase + lane], __ATOMIC_RELAXED,
                                                 __HIP_MEMORY_SCOPE_AGENT) == 0)
                            __builtin_amdgcn_s_sleep(2);
                    }
                    asm volatile("" ::: "memory");
                    // quad-grouped Horner, plain cached loads (write-once data)
                    const float* eb = evals + (size_t)seqbase * ND;
                    float l1 = lam32*lam32; l1 *= l1; l1 *= l1;   // lam^256
                    float l4 = l1 * l1; l4 *= l4;                 // lam^1024
                    float P = 0.f;
                    int j = 0;
                    const int rem = g & 3;
                    for (; j < rem; ++j)
                        P = fmaf(P, l1, eb[(size_t)j * ND + lane]);
                    for (; j < g; j += 4) {
                        float e0 = eb[(size_t)(j+0) * ND + lane];
                        float e1 = eb[(size_t)(j+1) * ND + lane];
                        float e2 = eb[(size_t)(j+2) * ND + lane];
                        float e3 = eb[(size_t)(j+3) * ND + lane];
                        float t = fmaf(fmaf(fmaf(e0, l1, e1), l1, e2), l1, e3);
                        P = fmaf(P, l4, t);
                    }
                    Hprev = P;
                }
            }
            hprev_lds[lane] = Hprev;
        }
        __syncthreads();

        // ---- carry per d-subgroup, vectorized final write (r13 form) ----
        {
            const int sr = lane >> 4;        // row within group of 4
            const int dg = lane & 15;        // d-group (4 consecutive d)
            float carry4[4];
            #pragma unroll
            for (int j2 = 0; j2 < 4; ++j2) {
                const int d = dg*4 + j2;
                float cy = 0.f, pw = 1.f;
                for (int j = 0; j < w; ++j) {
                    cy = fmaf(cy, lam32, ends_lds[j][d]);
                    pw *= lam32;
                }
                carry4[j2] = fmaf(pw, hprev_lds[d], cy);
            }
            const float lam2 = lam * lam, lam4 = lam2 * lam2;
            float f = lam;
            for (int j = 0; j < sr; ++j) f *= lam;   // lam^(sr+1)
            if (dir == 0) {
                float* p = ob + (size_t)(tr0 + r0 + sr) * ND + dg*4;
                #pragma unroll
                for (int q = 0; q < 8; ++q) {
                    u32x2 hv = *reinterpret_cast<const u32x2*>(
                        &xbuf[(r0 + q*4 + sr) * LDH + dg*4]);
                    f32x4 o;
                    o[0] = fmaf(f, carry4[0], bflo(hv[0]));
                    o[1] = fmaf(f, carry4[1], bfhi(hv[0]));
                    o[2] = fmaf(f, carry4[2], bflo(hv[1]));
                    o[3] = fmaf(f, carry4[3], bfhi(hv[1]));
                    *reinterpret_cast<f32x4*>(p + (size_t)q * 4 * ND) = o;
                    f *= lam4;
                }
            } else {
                float* p = ob + (size_t)(NT-1 - (tr0 + r0 + sr)) * ND + dg*4;
                #pragma unroll
                for (int q = 0; q < 8; ++q) {
                    u32x2 hv = *reinterpret_cast<const u32x2*>(
                        &xbuf[(r0 + q*4 + sr) * LDH + dg*4]);
                    f32x4 o;
                    o[0] = fmaf(f, carry4[0], bflo(hv[0]));
                    o[1] = fmaf(f, carry4[1], bfhi(hv[0]));
                    o[2] = fmaf(f, carry4[2], bflo(hv[1]));
                    o[3] = fmaf(f, carry4[3], bfhi(hv[1]));
                    *reinterpret_cast<f32x4*>(p - (size_t)q * 4 * ND) = o;
                    f *= lam4;
                }
            }
        }
        __syncthreads();   // xbuf/ends_lds/hprev_lds reuse safety
    }
}

extern "C" void kernel_launch(void* const* d_in, const int* in_sizes, int n_in,
                              void* d_out, int out_size, void* d_ws, size_t ws_size,
                              hipStream_t stream)
{
    const float* x  = (const float*)d_in[0];
    const float* Wf = (const float*)d_in[1];
    const float* bf = (const float*)d_in[2];
    const float* Wb = (const float*)d_in[3];
    const float* bb = (const float*)d_in[4];
    float* out = (float*)d_out;

    int*   flags = (int*)d_ws;                         // NSLOT ints (8 KiB)
    float* evals = (float*)((char*)d_ws + 16384);      // NSLOT*ND floats (512 KiB)

    Lams lams;
    const double delta = 13.0 / 7.0;   // log2(8192)/(C-1)
    for (int c = 0; c < 8; ++c)
        lams.v[c] = (float)(1.0 - pow(2.0, -(double)c * delta));

    // reset flags every launch (graph-replay safe, on-stream)
    hipMemsetAsync(flags, 0, NSLOT * 4, stream);

    dim3 grid(NBLK);   // 1024 blocks: (dir,c,b,kk), kk fastest — all resident
    k1_fused<<<grid, 512, 0, stream>>>(x, Wf, bf, Wb, bb, out, flags, evals, lams);
}